// Round 7
// baseline (66.063 us; speedup 1.0000x reference)
//
#include <hip/hip_runtime.h>
#include <hip/hip_bf16.h>

// DomainBatchNorm: out[b,f] = x[b,f] * scale[d(b),f] + shift[d(b),f]
// R7: R6 structure (block-per-row, f4/lane, sc0sc1nt bypass stores) +
// NON-TEMPORAL x loads. Goal: keep BOTH 128 MB streams from thrashing the
// 256 MB memory-side Infinity Cache (model: MALL port traffic ~10 TB/s is
// the wall, not HBM). Pure streaming floor: 257 MB @ 6.3 TB/s ~= 41 us.

#define F_DIM 1024
#define D_DIM 8
#define EPSV  1e-5f

typedef float f4 __attribute__((ext_vector_type(4)));

__device__ __forceinline__ void store_bypass(f4 v, f4* p) {
    // system-scope + non-temporal: write through, LRU-demote everywhere.
    asm volatile("global_store_dwordx4 %0, %1, off sc0 sc1 nt"
                 :: "v"(p), "v"(v)
                 : "memory");
}

__global__ __launch_bounds__(256) void DomainBatchNorm_kernel(
    const f4* __restrict__ x,        // [B, F/4]
    const float* __restrict__ mask,  // [B, D]
    const f4* __restrict__ gammas,   // [D, F/4]
    const f4* __restrict__ betas,
    const f4* __restrict__ means,
    const f4* __restrict__ vars,
    f4* __restrict__ out)            // [B, F/4]
{
    const int row = blockIdx.x;
    const int t   = threadIdx.x;        // 0..255, one float4 each (F=1024)

    // Resolve this row's domain: mask is exact one-hot, exactly one writer.
    __shared__ int sdom;
    if (t < D_DIM) {
        if (mask[(size_t)row * D_DIM + t] > 0.5f) sdom = t;
    }
    __syncthreads();
    const int d = sdom;

    const size_t prm = (size_t)d * (F_DIM / 4) + t;   // param index (f4 units)
    const size_t idx = (size_t)row * (F_DIM / 4) + t; // row-major x/out index

    const f4 g  = gammas[prm];
    const f4 bt = betas[prm];
    const f4 mu = means[prm];
    const f4 vr = vars[prm];
    // Non-temporal x load: streaming hint, don't displace/occupy cache.
    const f4 xv = __builtin_nontemporal_load(&x[idx]);

    f4 o;
    {
        float s;
        s   = g.x * rsqrtf(vr.x + EPSV); o.x = fmaf(xv.x, s, fmaf(-mu.x, s, bt.x));
        s   = g.y * rsqrtf(vr.y + EPSV); o.y = fmaf(xv.y, s, fmaf(-mu.y, s, bt.y));
        s   = g.z * rsqrtf(vr.z + EPSV); o.z = fmaf(xv.z, s, fmaf(-mu.z, s, bt.z));
        s   = g.w * rsqrtf(vr.w + EPSV); o.w = fmaf(xv.w, s, fmaf(-mu.w, s, bt.w));
    }
    store_bypass(o, &out[idx]);
}

extern "C" void kernel_launch(void* const* d_in, const int* in_sizes, int n_in,
                              void* d_out, int out_size, void* d_ws, size_t ws_size,
                              hipStream_t stream) {
    const float* x     = (const float*)d_in[0];
    const float* mask  = (const float*)d_in[1];
    const float* gam   = (const float*)d_in[2];
    const float* bet   = (const float*)d_in[3];
    const float* mu    = (const float*)d_in[4];
    const float* var   = (const float*)d_in[5];
    float* out         = (float*)d_out;

    const int B = in_sizes[0] / F_DIM;  // 32768

    DomainBatchNorm_kernel<<<B, 256, 0, stream>>>(
        (const f4*)x, mask,
        (const f4*)gam, (const f4*)bet,
        (const f4*)mu,  (const f4*)var,
        (f4*)out);
}

// Round 8
// 45.054 us; speedup vs baseline: 1.4663x; 1.4663x over previous
//
#include <hip/hip_runtime.h>
#include <hip/hip_bf16.h>

// DomainBatchNorm: out[b,f] = x[b,f] * scale[d(b),f] + shift[d(b),f]
// R8: exact R6 structure (block-per-row, f4/lane, default x loads), store
// flag A/B: "sc1 nt" (bypass per-XCD L2 + MALL LRU-demote) instead of
// R6's "sc0 sc1 nt" (drops system-scope, which may add coherence cost).
// Model: out stream must not claim MALL lines (they evict x, whose L3
// residency serves ~half the reads per replay); x loads stay default.

#define F_DIM 1024
#define D_DIM 8
#define EPSV  1e-5f

typedef float f4 __attribute__((ext_vector_type(4)));

__device__ __forceinline__ void store_bypass(f4 v, f4* p) {
    // device-scope (skip L2 write-allocate) + non-temporal (MALL demote).
    asm volatile("global_store_dwordx4 %0, %1, off sc1 nt"
                 :: "v"(p), "v"(v)
                 : "memory");
}

__global__ __launch_bounds__(256) void DomainBatchNorm_kernel(
    const f4* __restrict__ x,        // [B, F/4]
    const float* __restrict__ mask,  // [B, D]
    const f4* __restrict__ gammas,   // [D, F/4]
    const f4* __restrict__ betas,
    const f4* __restrict__ means,
    const f4* __restrict__ vars,
    f4* __restrict__ out)            // [B, F/4]
{
    const int row = blockIdx.x;
    const int t   = threadIdx.x;        // 0..255, one float4 each (F=1024)

    // Resolve this row's domain: mask is exact one-hot, exactly one writer.
    __shared__ int sdom;
    if (t < D_DIM) {
        if (mask[(size_t)row * D_DIM + t] > 0.5f) sdom = t;
    }
    __syncthreads();
    const int d = sdom;

    const size_t prm = (size_t)d * (F_DIM / 4) + t;   // param index (f4 units)
    const size_t idx = (size_t)row * (F_DIM / 4) + t; // row-major x/out index

    const f4 g  = gammas[prm];
    const f4 bt = betas[prm];
    const f4 mu = means[prm];
    const f4 vr = vars[prm];
    const f4 xv = x[idx];            // default load: let x allocate in MALL

    f4 o;
    {
        float s;
        s   = g.x * rsqrtf(vr.x + EPSV); o.x = fmaf(xv.x, s, fmaf(-mu.x, s, bt.x));
        s   = g.y * rsqrtf(vr.y + EPSV); o.y = fmaf(xv.y, s, fmaf(-mu.y, s, bt.y));
        s   = g.z * rsqrtf(vr.z + EPSV); o.z = fmaf(xv.z, s, fmaf(-mu.z, s, bt.z));
        s   = g.w * rsqrtf(vr.w + EPSV); o.w = fmaf(xv.w, s, fmaf(-mu.w, s, bt.w));
    }
    store_bypass(o, &out[idx]);
}

extern "C" void kernel_launch(void* const* d_in, const int* in_sizes, int n_in,
                              void* d_out, int out_size, void* d_ws, size_t ws_size,
                              hipStream_t stream) {
    const float* x     = (const float*)d_in[0];
    const float* mask  = (const float*)d_in[1];
    const float* gam   = (const float*)d_in[2];
    const float* bet   = (const float*)d_in[3];
    const float* mu    = (const float*)d_in[4];
    const float* var   = (const float*)d_in[5];
    float* out         = (float*)d_out;

    const int B = in_sizes[0] / F_DIM;  // 32768

    DomainBatchNorm_kernel<<<B, 256, 0, stream>>>(
        (const f4*)x, mask,
        (const f4*)gam, (const f4*)bet,
        (const f4*)mu,  (const f4*)var,
        (f4*)out);
}